// Round 2
// baseline (2120.390 us; speedup 1.0000x reference)
//
#include <hip/hip_runtime.h>
#include <stdint.h>

typedef unsigned short u16;
typedef unsigned int u32;

using bf8_t = __attribute__((ext_vector_type(8))) short;   // 8 bf16 (bit patterns)
using f4_t  = __attribute__((ext_vector_type(4))) float;

#define MFMA16(a,b,c) __builtin_amdgcn_mfma_f32_16x16x32_bf16((a),(b),(c),0,0,0)

__device__ __forceinline__ u16 f2bf(float f) {
  union { float f; u32 u; } v; v.f = f;
  u32 u = v.u;
  u += 0x7FFFu + ((u >> 16) & 1u);
  return (u16)(u >> 16);
}
__device__ __forceinline__ float bf2f(u16 h) {
  union { float f; u32 u; } v; v.u = ((u32)h) << 16; return v.f;
}
__device__ __forceinline__ float sigm(float x) {
  return __builtin_amdgcn_rcpf(1.f + __expf(-x));
}
__device__ __forceinline__ float tanh_f(float x) {
  x = fminf(30.f, fmaxf(-30.f, x));
  float e = __expf(-2.f * x);
  return (1.f - e) * __builtin_amdgcn_rcpf(1.f + e);
}

// ---------------- prep kernels ----------------

// C[128][128] = A[128][128] @ B[128][128]
__global__ void k_gemm128(const float* __restrict__ A, const float* __restrict__ B,
                          float* __restrict__ C) {
  int g = blockIdx.x * 256 + threadIdx.x;   // 4096 threads
  int row = g >> 5;
  int c0 = (g & 31) << 2;
  f4_t acc = {0.f, 0.f, 0.f, 0.f};
  for (int k = 0; k < 128; ++k) {
    float a = A[row * 128 + k];
    acc += a * *(const f4_t*)&B[k * 128 + c0];
  }
  *(f4_t*)&C[row * 128 + c0] = acc;
}

// WB[256][384] = [fc_W | fc_W@B2 | fc_W@B3]
__global__ void k_wbig(const float* __restrict__ fc_W, const float* __restrict__ B2,
                       const float* __restrict__ B3, float* __restrict__ WB) {
  int g = blockIdx.x * 256 + threadIdx.x;   // 24576
  int row = g / 96;
  int j0 = (g % 96) * 4;
  if (j0 < 128) {
    *(f4_t*)&WB[row * 384 + j0] = *(const f4_t*)&fc_W[row * 128 + j0];
  } else {
    const float* Bm = (j0 < 256) ? B2 : B3;
    int jj = j0 & 127;
    f4_t acc = {0.f, 0.f, 0.f, 0.f};
    for (int n = 0; n < 128; ++n)
      acc += fc_W[row * 128 + n] * *(const f4_t*)&Bm[n * 128 + jj];
    *(f4_t*)&WB[row * 384 + j0] = acc;
  }
}

// bb[384] = [fc_b | fc_b@B2 + fc2_b@Wq2 | fc_b@B3 + fc2_b@Wk3]
__global__ void k_bbig(const float* __restrict__ fc_b, const float* __restrict__ fc2_b,
                       const float* __restrict__ B2, const float* __restrict__ B3,
                       const float* __restrict__ Wq2, const float* __restrict__ Wk3,
                       float* __restrict__ bb) {
  int j = blockIdx.x * 256 + threadIdx.x;
  if (j >= 384) return;
  if (j < 128) { bb[j] = fc_b[j]; return; }
  const float* Bm = (j < 256) ? B2 : B3;
  const float* Wm = (j < 256) ? Wq2 : Wk3;
  int jj = j & 127;
  float acc = 0.f;
  for (int n = 0; n < 128; ++n)
    acc += fc_b[n] * Bm[n * 128 + jj] + fc2_b[n] * Wm[n * 128 + jj];
  bb[j] = acc;
}

// SK[1002][384] = skill_emb @ WB[0:128]; DF[102][384] = diff_emb @ WB[128:256] + bb
__global__ void k_skdf(const float* __restrict__ skill_emb, const float* __restrict__ diff_emb,
                       const float* __restrict__ WB, const float* __restrict__ bb,
                       float* __restrict__ SK, float* __restrict__ DF) {
  int g = blockIdx.x * 256 + threadIdx.x;
  int row = g / 96, j0 = (g % 96) * 4;
  if (blockIdx.y == 0) {
    if (row >= 1002) return;
    f4_t acc = {0.f, 0.f, 0.f, 0.f};
    for (int d = 0; d < 128; ++d)
      acc += skill_emb[row * 128 + d] * *(const f4_t*)&WB[d * 384 + j0];
    *(f4_t*)&SK[row * 384 + j0] = acc;
  } else {
    if (row >= 102) return;
    f4_t acc = *(const f4_t*)&bb[j0];
    for (int d = 0; d < 128; ++d)
      acc += diff_emb[row * 128 + d] * *(const f4_t*)&WB[(128 + d) * 384 + j0];
    *(f4_t*)&DF[row * 384 + j0] = acc;
  }
}

// Tv2[12][128] = hints_emb @ Wv2 ; Tv3[3][128] = answer_emb @ Wv3
__global__ void k_tv(const float* __restrict__ hints_emb, const float* __restrict__ Wv2,
                     const float* __restrict__ answer_emb, const float* __restrict__ Wv3,
                     float* __restrict__ Tv2, float* __restrict__ Tv3) {
  int g = blockIdx.x * 256 + threadIdx.x;
  if (g < 384) {
    int i = g >> 5, j0 = (g & 31) << 2;
    f4_t acc = {0.f, 0.f, 0.f, 0.f};
    for (int d = 0; d < 128; ++d)
      acc += hints_emb[i * 128 + d] * *(const f4_t*)&Wv2[d * 128 + j0];
    *(f4_t*)&Tv2[i * 128 + j0] = acc;
  } else if (g < 480) {
    int g2 = g - 384;
    int i = g2 >> 5, j0 = (g2 & 31) << 2;
    f4_t acc = {0.f, 0.f, 0.f, 0.f};
    for (int d = 0; d < 128; ++d)
      acc += answer_emb[i * 128 + d] * *(const f4_t*)&Wv3[d * 128 + j0];
    *(f4_t*)&Tv3[i * 128 + j0] = acc;
  }
}

// Pack in-loop weights into per-lane MFMA A-fragment order.
// whi: 8 mats {A2,A3,Wq3,Wk2,f11,f12,f21,f22} bf16 hi
// flo: same 8 mats, bf16 lo residual
struct P8 { const float* p[8]; };
__global__ void k_pack(P8 s, u16* __restrict__ whi, u16* __restrict__ flo) {
  int g = blockIdx.x * 256 + threadIdx.x;   // 128*256 = 32768
  bool lo = (g >= 16384);
  int gg = g & 16383;
  int m = gg >> 11;
  int r = gg & 2047;
  int kk = r >> 9, w = (r >> 6) & 7, l = r & 63;
  const float* src = s.p[m];
  int col = w * 16 + (l & 15);
  int kbase = kk * 32 + ((l >> 4) << 3);
  u16 o[8];
  #pragma unroll
  for (int e = 0; e < 8; ++e) {
    float v = src[(kbase + e) * 128 + col];
    u16 h = f2bf(v);
    o[e] = lo ? f2bf(v - bf2f(h)) : h;
  }
  u16* dst = (lo ? flo : whi) + gg * 8;
  uint4 u;
  u.x = o[0] | ((u32)o[1] << 16); u.y = o[2] | ((u32)o[3] << 16);
  u.z = o[4] | ((u32)o[5] << 16); u.w = o[6] | ((u32)o[7] << 16);
  *(uint4*)dst = u;
}

// ---------------- main recurrent kernel ----------------
// 32 blocks x 512 threads. Block b owns batch rows 16b..16b+15.
// Wave w owns feature columns [16w,16w+16) of every in-loop matrix (register A-frags,
// hi+lo). All matmuls transposed: C^T[feat][row] = W^T @ act^T (MFMA 16x16x32 bf16),
// activations kept as hi+lo bf16 pairs in LDS; 3-term products close the quantization
// error (residual ~2^-17 relative).

__launch_bounds__(512, 1)
__global__ void k_main(const int* __restrict__ skill, const int* __restrict__ answer,
                       const int* __restrict__ diff, const int* __restrict__ hints,
                       const float* __restrict__ SK, const float* __restrict__ DF,
                       const float* __restrict__ Tv2, const float* __restrict__ Tv3,
                       const u16* __restrict__ whi, const u16* __restrict__ flo,
                       const float* __restrict__ b11p, const float* __restrict__ b12p,
                       const float* __restrict__ b21p, const float* __restrict__ b22p,
                       float* __restrict__ out) {
  __shared__ u16 sh_h[2048], sh_hl[2048], sh_c[2048], sh_cl[2048];
  __shared__ u16 sh_oh[2048], sh_ol[2048], sh_o3[2048], sh_o3l[2048];
  __shared__ float sh_tv2[12 * 132];
  __shared__ float sh_tv3[3 * 132];
  __shared__ float sh_bias[512];
  __shared__ float sh_red[16 * 8];
  __shared__ float sh_y[16 * 200];

  const int tid = threadIdx.x;
  const int w = tid >> 6, lane = tid & 63;
  const int row = lane & 15;
  const int fgrp = lane >> 4;
  const int f0 = w * 16 + fgrp * 4;
  const int row_g = blockIdx.x * 16 + row;
  const int r200 = row_g * 200;

  // register-resident weight fragments (hi + lo)
  bf8_t wf[8][4], wl[8][4];
  #pragma unroll
  for (int m = 0; m < 8; ++m)
    #pragma unroll
    for (int kk = 0; kk < 4; ++kk) {
      int idx = (((m * 4 + kk) * 8 + w) * 64 + lane) * 8;
      wf[m][kk] = *(const bf8_t*)&whi[idx];
      wl[m][kk] = *(const bf8_t*)&flo[idx];
    }

  // LDS init
  for (int i = tid; i < 1024; i += 512) {
    ((u32*)sh_h)[i] = 0u; ((u32*)sh_hl)[i] = 0u;
    ((u32*)sh_c)[i] = 0u; ((u32*)sh_cl)[i] = 0u;
  }
  for (int i = tid; i < 12 * 128; i += 512) sh_tv2[(i >> 7) * 132 + (i & 127)] = Tv2[i];
  for (int i = tid; i < 3 * 128; i += 512) sh_tv3[(i >> 7) * 132 + (i & 127)] = Tv3[i];
  if (tid < 128) {
    sh_bias[tid]       = b11p[tid];
    sh_bias[128 + tid] = b12p[tid];
    sh_bias[256 + tid] = b21p[tid];
    sh_bias[384 + tid] = b22p[tid];
  }

  f4_t cst = {0.f, 0.f, 0.f, 0.f};   // fp32 c state (this lane's 4 feats x its row)

  // prologue prefetch
  int i_h0 = hints[r200];
  int i_a0 = answer[r200];
  int s0 = skill[r200], d0 = diff[r200];
  int i_s1 = skill[r200 + 1], i_d1 = diff[r200 + 1];
  int i_s2 = skill[r200 + 2], i_d2 = diff[r200 + 2];
  f4_t skq2 = *(const f4_t*)&SK[s0 * 384 + 128 + f0];
  f4_t dfq2 = *(const f4_t*)&DF[d0 * 384 + 128 + f0];
  f4_t skq3 = *(const f4_t*)&SK[s0 * 384 + 256 + f0];
  f4_t dfq3 = *(const f4_t*)&DF[d0 * 384 + 256 + f0];
  f4_t skxn = *(const f4_t*)&SK[i_s1 * 384 + f0];
  f4_t dfxn = *(const f4_t*)&DF[i_d1 * 384 + f0];
  __syncthreads();

  const float inv = 0.088388347648318447f;  // 1/sqrt(128)
  const int swz = (row & 7) << 3;
  const int rbase = row * 128;
  const int widx = (rbase + f0) ^ swz;

  for (int t = 0; t < 199; ++t) {
    // ---- stage 1: q2 = XQ2 + h@A2 ; q3 = XQ3 + h@A3 ; k3 = h@Wq3 ; k2 = c@Wk2 ----
    f4_t q2a = skq2 + dfq2;
    f4_t q3a = skq3 + dfq3;
    f4_t k3a = {0.f, 0.f, 0.f, 0.f};
    f4_t k2a = {0.f, 0.f, 0.f, 0.f};
    #pragma unroll
    for (int kk = 0; kk < 4; ++kk) {
      int ridx = (rbase + kk * 32 + fgrp * 8) ^ swz;
      bf8_t hh = *(const bf8_t*)&sh_h[ridx];
      bf8_t hl = *(const bf8_t*)&sh_hl[ridx];
      bf8_t ch = *(const bf8_t*)&sh_c[ridx];
      bf8_t cl = *(const bf8_t*)&sh_cl[ridx];
      q2a = MFMA16(wf[0][kk], hh, q2a);
      q2a = MFMA16(wf[0][kk], hl, q2a);
      q2a = MFMA16(wl[0][kk], hh, q2a);
      q3a = MFMA16(wf[1][kk], hh, q3a);
      q3a = MFMA16(wf[1][kk], hl, q3a);
      q3a = MFMA16(wl[1][kk], hh, q3a);
      k3a = MFMA16(wf[2][kk], hh, k3a);
      k3a = MFMA16(wf[2][kk], hl, k3a);
      k3a = MFMA16(wl[2][kk], hh, k3a);
      k2a = MFMA16(wf[3][kk], ch, k2a);
      k2a = MFMA16(wf[3][kk], cl, k2a);
      k2a = MFMA16(wl[3][kk], ch, k2a);
    }

    // ---- E1: prefetches + gates + write out/o3 (hi+lo) to LDS ----
    int tn = (t + 3 < 199) ? (t + 3) : 199;
    int n_s = skill[r200 + tn];
    int n_d = diff[r200 + tn];
    int th = (t + 1 < 199) ? (t + 1) : 198;
    int n_h = hints[r200 + th];
    int n_a = answer[r200 + th];
    f4_t nskq2 = *(const f4_t*)&SK[i_s1 * 384 + 128 + f0];
    f4_t ndfq2 = *(const f4_t*)&DF[i_d1 * 384 + 128 + f0];
    f4_t nskq3 = *(const f4_t*)&SK[i_s1 * 384 + 256 + f0];
    f4_t ndfq3 = *(const f4_t*)&DF[i_d1 * 384 + 256 + f0];
    f4_t nskxn = *(const f4_t*)&SK[i_s2 * 384 + f0];
    f4_t ndfxn = *(const f4_t*)&DF[i_d2 * 384 + f0];
    f4_t v2 = *(const f4_t*)&sh_tv2[i_h0 * 132 + f0];
    f4_t v3 = *(const f4_t*)&sh_tv3[i_a0 * 132 + f0];

    u16 oh[4], ol[4], o3h[4], o3l[4];
    #pragma unroll
    for (int r = 0; r < 4; ++r) {
      float ov = v2[r] * sigm(q2a[r] * k2a[r] * inv);
      float o3v = v3[r] * sigm(q3a[r] * k3a[r] * inv);
      oh[r] = f2bf(ov);
      ol[r] = f2bf(ov - bf2f(oh[r]));
      o3h[r] = f2bf(o3v);
      o3l[r] = f2bf(o3v - bf2f(o3h[r]));
    }
    uint2 pk;
    pk.x = oh[0] | ((u32)oh[1] << 16); pk.y = oh[2] | ((u32)oh[3] << 16);
    *(uint2*)&sh_oh[widx] = pk;
    pk.x = ol[0] | ((u32)ol[1] << 16); pk.y = ol[2] | ((u32)ol[3] << 16);
    *(uint2*)&sh_ol[widx] = pk;
    pk.x = o3h[0] | ((u32)o3h[1] << 16); pk.y = o3h[2] | ((u32)o3h[3] << 16);
    *(uint2*)&sh_o3[widx] = pk;
    pk.x = o3l[0] | ((u32)o3l[1] << 16); pk.y = o3l[2] | ((u32)o3l[3] << 16);
    *(uint2*)&sh_o3l[widx] = pk;
    __syncthreads();

    // ---- stage 2: pre = out@[f11|f12], o3@[f21|f22] (3-term bf16x2 each) ----
    f4_t a11 = *(const f4_t*)&sh_bias[0 + f0];
    f4_t a12 = *(const f4_t*)&sh_bias[128 + f0];
    f4_t a21 = *(const f4_t*)&sh_bias[256 + f0];
    f4_t a22 = *(const f4_t*)&sh_bias[384 + f0];
    #pragma unroll
    for (int kk = 0; kk < 4; ++kk) {
      int ridx = (rbase + kk * 32 + fgrp * 8) ^ swz;
      bf8_t ohf = *(const bf8_t*)&sh_oh[ridx];
      bf8_t olf = *(const bf8_t*)&sh_ol[ridx];
      bf8_t o3f = *(const bf8_t*)&sh_o3[ridx];
      bf8_t o3lf = *(const bf8_t*)&sh_o3l[ridx];
      a11 = MFMA16(wf[4][kk], ohf, a11);
      a11 = MFMA16(wf[4][kk], olf, a11);
      a11 = MFMA16(wl[4][kk], ohf, a11);
      a12 = MFMA16(wf[5][kk], ohf, a12);
      a12 = MFMA16(wf[5][kk], olf, a12);
      a12 = MFMA16(wl[5][kk], ohf, a12);
      a21 = MFMA16(wf[6][kk], o3f, a21);
      a21 = MFMA16(wf[6][kk], o3lf, a21);
      a21 = MFMA16(wl[6][kk], o3f, a21);
      a22 = MFMA16(wf[7][kk], o3f, a22);
      a22 = MFMA16(wf[7][kk], o3lf, a22);
      a22 = MFMA16(wl[7][kk], o3f, a22);
    }

    // ---- E2: state update + y partial + write h,c (hi+lo) ----
    f4_t xn = skxn + dfxn;
    float part = 0.f;
    f4_t hv;
    #pragma unroll
    for (int r = 0; r < 4; ++r) {
      float g = tanh_f(a11[r]) * sigm(a12[r]);
      cst[r] += g;
      float hh = tanh_f(a21[r]) * sigm(a22[r]) + cst[r];
      hv[r] = hh;
      part += xn[r] * hh;
    }
    part += __shfl_xor(part, 16);
    part += __shfl_xor(part, 32);
    if (lane < 16) sh_red[lane * 8 + w] = part;

    u16 hb[4], hlb[4], cb[4], clb[4];
    #pragma unroll
    for (int r = 0; r < 4; ++r) {
      hb[r] = f2bf(hv[r]);
      hlb[r] = f2bf(hv[r] - bf2f(hb[r]));
      cb[r] = f2bf(cst[r]);
      clb[r] = f2bf(cst[r] - bf2f(cb[r]));
    }
    pk.x = hb[0] | ((u32)hb[1] << 16); pk.y = hb[2] | ((u32)hb[3] << 16);
    *(uint2*)&sh_h[widx] = pk;
    pk.x = hlb[0] | ((u32)hlb[1] << 16); pk.y = hlb[2] | ((u32)hlb[3] << 16);
    *(uint2*)&sh_hl[widx] = pk;
    pk.x = cb[0] | ((u32)cb[1] << 16); pk.y = cb[2] | ((u32)cb[3] << 16);
    *(uint2*)&sh_c[widx] = pk;
    pk.x = clb[0] | ((u32)clb[1] << 16); pk.y = clb[2] | ((u32)clb[3] << 16);
    *(uint2*)&sh_cl[widx] = pk;

    // rotate prefetch
    i_h0 = n_h; i_a0 = n_a;
    i_s1 = i_s2; i_d1 = i_d2; i_s2 = n_s; i_d2 = n_d;
    skq2 = nskq2; dfq2 = ndfq2; skq3 = nskq3; dfq3 = ndfq3; skxn = nskxn; dfxn = ndfxn;
    __syncthreads();

    // ---- Y: finalize y[:, t] (wave 0) ----
    if (w == 0 && lane < 16) {
      const f4_t p0 = *(const f4_t*)&sh_red[lane * 8];
      const f4_t p1 = *(const f4_t*)&sh_red[lane * 8 + 4];
      float sfull = ((p0[0] + p0[1]) + (p0[2] + p0[3])) + ((p1[0] + p1[1]) + (p1[2] + p1[3]));
      sh_y[lane * 200 + t] = sigm(sfull);
    }
  }
  __syncthreads();

  // flush y buffer (col 199 = 0)
  for (int i = tid; i < 3200; i += 512) {
    int r = i / 200, tt = i % 200;
    out[(blockIdx.x * 16 + r) * 200 + tt] = (tt < 199) ? sh_y[i] : 0.f;
  }
}

// ---------------- launcher ----------------

extern "C" void kernel_launch(void* const* d_in, const int* in_sizes, int n_in,
                              void* d_out, int out_size, void* d_ws, size_t ws_size,
                              hipStream_t stream) {
  const int* skill  = (const int*)d_in[0];
  const int* answer = (const int*)d_in[1];
  const int* diff   = (const int*)d_in[2];
  const int* hints  = (const int*)d_in[3];
  const float* skill_emb  = (const float*)d_in[5];
  const float* answer_emb = (const float*)d_in[6];
  const float* diff_emb   = (const float*)d_in[7];
  const float* hints_emb  = (const float*)d_in[8];
  const float* Wq2 = (const float*)d_in[10];
  const float* Wk2 = (const float*)d_in[11];
  const float* Wv2 = (const float*)d_in[12];
  const float* Wq3 = (const float*)d_in[13];
  const float* Wk3 = (const float*)d_in[14];
  const float* Wv3 = (const float*)d_in[15];
  const float* fc_W  = (const float*)d_in[16];
  const float* fc_b  = (const float*)d_in[17];
  const float* fc2_W = (const float*)d_in[18];
  const float* fc2_b = (const float*)d_in[19];
  const float* f11_W = (const float*)d_in[20];
  const float* f11_b = (const float*)d_in[21];
  const float* f12_W = (const float*)d_in[22];
  const float* f12_b = (const float*)d_in[23];
  const float* f21_W = (const float*)d_in[24];
  const float* f21_b = (const float*)d_in[25];
  const float* f22_W = (const float*)d_in[26];
  const float* f22_b = (const float*)d_in[27];

  float* ws = (float*)d_ws;
  float* A2 = ws + 0;          // 128x128
  float* A3 = ws + 16384;
  float* B2 = ws + 32768;
  float* B3 = ws + 49152;
  float* WB = ws + 65536;      // 256x384
  float* BB = ws + 163840;     // 384
  float* SKt = ws + 164224;    // 1002x384
  float* DFt = ws + 548992;    // 102x384
  float* TV2 = ws + 588160;    // 12x128
  float* TV3 = ws + 589696;    // 3x128
  u16* WHI = (u16*)((char*)d_ws + 2360320);  // 256 KB
  u16* FLO = (u16*)((char*)d_ws + 2622464);  // 256 KB
  float* outp = (float*)d_out;

  k_gemm128<<<16, 256, 0, stream>>>(fc2_W,         Wq2, B2);
  k_gemm128<<<16, 256, 0, stream>>>(fc2_W,         Wk3, B3);
  k_gemm128<<<16, 256, 0, stream>>>(fc2_W + 16384, Wq2, A2);
  k_gemm128<<<16, 256, 0, stream>>>(fc2_W + 16384, Wk3, A3);
  k_wbig<<<96, 256, 0, stream>>>(fc_W, B2, B3, WB);
  k_bbig<<<2, 256, 0, stream>>>(fc_b, fc2_b, B2, B3, Wq2, Wk3, BB);
  k_skdf<<<dim3(376, 2), 256, 0, stream>>>(skill_emb, diff_emb, WB, BB, SKt, DFt);
  k_tv<<<2, 256, 0, stream>>>(hints_emb, Wv2, answer_emb, Wv3, TV2, TV3);
  P8 s;
  s.p[0] = A2; s.p[1] = A3; s.p[2] = Wq3; s.p[3] = Wk2;
  s.p[4] = f11_W; s.p[5] = f12_W; s.p[6] = f21_W; s.p[7] = f22_W;
  k_pack<<<128, 256, 0, stream>>>(s, WHI, FLO);
  k_main<<<32, 512, 0, stream>>>(skill, answer, diff, hints, SKt, DFt, TV2, TV3,
                                 WHI, FLO, f11_b, f12_b, f21_b, f22_b, outp);
}